// Round 2
// baseline (157.304 us; speedup 1.0000x reference)
//
#include <hip/hip_runtime.h>
#include <stdint.h>

#define K_DIM 4096
#define N_DIM 11008
#define M_DIM 256
#define BK 64
#define BN 64
#define BM 128
#define NT (K_DIM / BK)   // 64 K-tiles

typedef uint32_t u32;
using frag_ab = __attribute__((ext_vector_type(8))) short;   // 8 bf16 (4 VGPR)
using frag_cd = __attribute__((ext_vector_type(4))) float;   // 4 f32 acc

__device__ __forceinline__ u32 f2bf_rn(float f) {
    u32 u = __builtin_bit_cast(u32, f);
    return (u + 0x7FFFu + ((u >> 16) & 1u)) >> 16;   // round-to-nearest-even
}
__device__ __forceinline__ float bf2f(u32 b) {
    return __builtin_bit_cast(float, b << 16);
}

__device__ __forceinline__ void gll16(const u32* g, u32* l) {
    __builtin_amdgcn_global_load_lds(
        (const __attribute__((address_space(1))) u32*)g,
        (__attribute__((address_space(3))) u32*)l, 16, 0, 0);
}

// Kernel 1: x f32 -> bf16 (RN) + per-row sums of the ROUNDED values.
__global__ __launch_bounds__(256) void prep_kernel(const float* __restrict__ x,
                                                   ushort* __restrict__ xbf,
                                                   float* __restrict__ rowsum) {
    const int row = blockIdx.x;
    const int tid = threadIdx.x;
    const float* xr = x + (size_t)row * K_DIM;
    ushort* br = xbf + (size_t)row * K_DIM;
    float s = 0.0f;
#pragma unroll
    for (int p = 0; p < 4; ++p) {
        int i = p * 1024 + tid * 4;
        float4 v = *reinterpret_cast<const float4*>(xr + i);
        u32 b0 = f2bf_rn(v.x), b1 = f2bf_rn(v.y), b2 = f2bf_rn(v.z), b3 = f2bf_rn(v.w);
        uint2 o;
        o.x = b0 | (b1 << 16);
        o.y = b2 | (b3 << 16);
        *reinterpret_cast<uint2*>(br + i) = o;
        s += bf2f(b0) + bf2f(b1) + bf2f(b2) + bf2f(b3);
    }
#pragma unroll
    for (int off = 32; off > 0; off >>= 1) s += __shfl_down(s, off, 64);
    __shared__ float wsum[4];
    if ((tid & 63) == 0) wsum[tid >> 6] = s;
    __syncthreads();
    if (tid == 0) rowsum[row] = wsum[0] + wsum[1] + wsum[2] + wsum[3];
}

// Kernel 2: out = xbf @ dequant(qw).  BM=128, BN=64, BK=64. 4 waves (2m x 2n),
// wave tile 64m x 32n.  Packed qweight dwords staged async into LDS via
// global_load_lds (source-side XOR swizzle so ds_read_b32 is conflict-free);
// nibble->bf16 unpack happens at the register level on the consume side.
__global__ __launch_bounds__(256) void gemm_kernel(const int* __restrict__ qw,
                                                   const float* __restrict__ scales,
                                                   const float* __restrict__ zeroes,
                                                   const ushort* __restrict__ xbf,
                                                   const float* __restrict__ rowsum,
                                                   float* __restrict__ out) {
    // LDS: packed B tile, dword (row, n) at [row*64 + (n ^ (((row>>2)&3)<<3))]
    __shared__ u32 Bt[2][2048];   // 2 x 8 KB

    const int tid  = threadIdx.x;
    const int lane = tid & 63;
    const int wid  = tid >> 6;

    // XCD-bijective swizzle: 344 blocks = 43 chunks x 8 XCDs; consecutive wg
    // (the two M-halves of one n-tile) land on the same XCD.
    const int orig = blockIdx.x;
    const int wg   = (orig & 7) * 43 + (orig >> 3);
    const int nb   = wg >> 1;          // 0..171
    const int mb   = wg & 1;           // 0..1
    const int n0   = nb * BN;
    const int m0   = mb * BM;

    const int wm = wid >> 1;           // 0..1  (64-row slab)
    const int wn = wid & 1;            // 0..1  (32-col slab)

    // ---- staging: wave w, round s stages local rows (w*2+s)*4 + (lane>>4),
    // 4 consecutive n-dwords per lane, source pre-swizzled (XOR bits 3..4).
    const int c_st   = lane >> 4;
    int src_n[2];
    int row_st[2];
#pragma unroll
    for (int s = 0; s < 2; ++s) {
        int grp = wid * 2 + s;                        // 0..7 (= row>>2)
        row_st[s] = grp * 4 + c_st;                   // local packed row 0..31
        src_n[s]  = (((lane & 15) << 2) ^ ((grp & 3) << 3)) + n0;
    }

    // ---- B read offsets (dwords): row0 = ks*16 + c*4, swz = c<<3 (row>>2
    // == ks*4 + c, &3 == c).  addr_j = boff + j*64.
    const int c = lane >> 4;
    int boff[2][2];
#pragma unroll
    for (int ks = 0; ks < 2; ++ks)
#pragma unroll
        for (int nf = 0; nf < 2; ++nf) {
            int n_local = wn * 32 + nf * 16 + (lane & 15);
            boff[ks][nf] = (ks * 16 + c * 4) * 64 + (n_local ^ (c << 3));
        }

    // ---- A fragment base: lane holds A[m = l&15][k-chunk (l>>4)*8 .. +7]
    const ushort* abase = xbf + (size_t)(m0 + wm * 64 + (lane & 15)) * K_DIM + (c * 8);

    frag_cd acc[4][2];
#pragma unroll
    for (int a = 0; a < 4; ++a)
#pragma unroll
        for (int b = 0; b < 2; ++b)
            acc[a][b] = (frag_cd){0.f, 0.f, 0.f, 0.f};

    frag_ab afA[4][2], afB[4][2];

    auto stage = [&](int t, int buf) {
#pragma unroll
        for (int s = 0; s < 2; ++s) {
            const u32* src = (const u32*)qw +
                             (size_t)(t * 32 + row_st[s]) * N_DIM + src_n[s];
            u32* dst = &Bt[buf][(wid * 2 + s) * 256];   // wave-uniform base
            gll16(src, dst);
        }
    };
    auto loadA = [&](frag_ab (&af)[4][2], int t) {
#pragma unroll
        for (int mf = 0; mf < 4; ++mf)
#pragma unroll
            for (int ks = 0; ks < 2; ++ks)
                af[mf][ks] = *reinterpret_cast<const frag_ab*>(
                    abase + (size_t)mf * 16 * K_DIM + t * 64 + ks * 32);
    };
    auto compute = [&](frag_ab (&af)[4][2], const u32* bufp) {
#pragma unroll
        for (int ks = 0; ks < 2; ++ks)
#pragma unroll
            for (int nf = 0; nf < 2; ++nf) {
                const u32* p = bufp + boff[ks][nf];
                u32 q0 = p[0], q1 = p[64], q2 = p[128], q3 = p[192];
                union { frag_ab f; u32 u[4]; } bb;
                // bf16(32 + nibble) = 0x4200 | (nibble << 2); lo nib = even k.
                bb.u[0] = 0x42004200u | ((q0 & 15u) << 2) | ((q0 & 0xF0u) << 14);
                bb.u[1] = 0x42004200u | ((q1 & 15u) << 2) | ((q1 & 0xF0u) << 14);
                bb.u[2] = 0x42004200u | ((q2 & 15u) << 2) | ((q2 & 0xF0u) << 14);
                bb.u[3] = 0x42004200u | ((q3 & 15u) << 2) | ((q3 & 0xF0u) << 14);
#pragma unroll
                for (int mf = 0; mf < 4; ++mf)
                    acc[mf][nf] = __builtin_amdgcn_mfma_f32_16x16x32_bf16(
                        af[mf][ks], bb.f, acc[mf][nf], 0, 0, 0);
            }
    };

    // prologue
    stage(0, 0);
    loadA(afA, 0);
    __syncthreads();

    // 2-phase pipeline, explicit 2x unroll (no runtime-indexed frag arrays)
    for (int t = 0; t < NT; t += 2) {
        if (t + 1 < NT) { stage(t + 1, 1); loadA(afB, t + 1); }
        compute(afA, &Bt[0][0]);
        __syncthreads();
        if (t + 1 < NT) {
            if (t + 2 < NT) { stage(t + 2, 0); loadA(afA, t + 2); }
            compute(afB, &Bt[1][0]);
            __syncthreads();
        }
    }

    // epilogue: out = sc*acc - (32*sc + zero)*rowsum
    const int ncol = lane & 15;
    const int rgrp = lane >> 4;
    float sc[2], zp[2];
#pragma unroll
    for (int nf = 0; nf < 2; ++nf) {
        int n = n0 + wn * 32 + nf * 16 + ncol;
        sc[nf] = scales[n];
        zp[nf] = zeroes[n] + 32.0f * sc[nf];
    }
    float rs[4][4];
#pragma unroll
    for (int mf = 0; mf < 4; ++mf)
#pragma unroll
        for (int j = 0; j < 4; ++j)
            rs[mf][j] = rowsum[m0 + wm * 64 + mf * 16 + rgrp * 4 + j];
#pragma unroll
    for (int mf = 0; mf < 4; ++mf)
#pragma unroll
        for (int nf = 0; nf < 2; ++nf)
#pragma unroll
            for (int j = 0; j < 4; ++j) {
                int m = m0 + wm * 64 + mf * 16 + rgrp * 4 + j;
                int n = n0 + wn * 32 + nf * 16 + ncol;
                out[(size_t)m * N_DIM + n] = sc[nf] * acc[mf][nf][j] - zp[nf] * rs[mf][j];
            }
}

extern "C" void kernel_launch(void* const* d_in, const int* in_sizes, int n_in,
                              void* d_out, int out_size, void* d_ws, size_t ws_size,
                              hipStream_t stream) {
    const float* x      = (const float*)d_in[0];
    const int*   qw     = (const int*)d_in[1];
    const float* scales = (const float*)d_in[2];
    const float* zeroes = (const float*)d_in[3];
    float* out = (float*)d_out;

    ushort* xbf    = (ushort*)d_ws;                                     // 2 MB
    float*  rowsum = (float*)((char*)d_ws + (size_t)M_DIM * K_DIM * 2); // 1 KB

    prep_kernel<<<M_DIM, 256, 0, stream>>>(x, xbf, rowsum);
    gemm_kernel<<<(N_DIM / BN) * (M_DIM / BM), 256, 0, stream>>>(
        qw, scales, zeroes, xbf, rowsum, out);
}

// Round 3
// 141.424 us; speedup vs baseline: 1.1123x; 1.1123x over previous
//
#include <hip/hip_runtime.h>
#include <stdint.h>

#define K_DIM 4096
#define N_DIM 11008
#define M_DIM 256
#define NS 128                 // K split into 128 steps of 32
#define STRD ((size_t)16 * N_DIM)   // packed-row stride per step (dwords)

typedef uint32_t u32;
using frag_ab = __attribute__((ext_vector_type(8))) short;   // 8 bf16
using frag_cd = __attribute__((ext_vector_type(4))) float;   // 4 f32

__device__ __forceinline__ u32 f2bf_rn(float f) {
    u32 u = __builtin_bit_cast(u32, f);
    return (u + 0x7FFFu + ((u >> 16) & 1u)) >> 16;   // round-to-nearest-even
}
__device__ __forceinline__ float bf2f(u32 b) {
    return __builtin_bit_cast(float, b << 16);
}

// Kernel 1: x f32 -> bf16 (RN) + per-row sums of the ROUNDED values (so the
// +32 trick's rank-1 correction cancels exactly).
__global__ __launch_bounds__(256) void prep_kernel(const float* __restrict__ x,
                                                   ushort* __restrict__ xbf,
                                                   float* __restrict__ rowsum) {
    const int row = blockIdx.x;
    const int tid = threadIdx.x;
    const float* xr = x + (size_t)row * K_DIM;
    ushort* br = xbf + (size_t)row * K_DIM;
    float s = 0.0f;
#pragma unroll
    for (int p = 0; p < 4; ++p) {
        int i = p * 1024 + tid * 4;
        float4 v = *reinterpret_cast<const float4*>(xr + i);
        u32 b0 = f2bf_rn(v.x), b1 = f2bf_rn(v.y), b2 = f2bf_rn(v.z), b3 = f2bf_rn(v.w);
        uint2 o;
        o.x = b0 | (b1 << 16);
        o.y = b2 | (b3 << 16);
        *reinterpret_cast<uint2*>(br + i) = o;
        s += bf2f(b0) + bf2f(b1) + bf2f(b2) + bf2f(b3);
    }
#pragma unroll
    for (int off = 32; off > 0; off >>= 1) s += __shfl_down(s, off, 64);
    __shared__ float wsum[4];
    if ((tid & 63) == 0) wsum[tid >> 6] = s;
    __syncthreads();
    if (tid == 0) rowsum[row] = wsum[0] + wsum[1] + wsum[2] + wsum[3];
}

// bf16(32+v) = 0x4200 | (v<<2).  For a byte q (hi<<4|lo):
// q*0x4004 = q<<14 | q<<2 (exact, no carries); mask keeps lo<<2 at bits 2-5
// and hi at bits 18-21 -> packed bf16x2 {32+lo, 32+hi} in one dword.
#define BFCVT(q) ((u32)((__mul24((int)(q), 0x4004) & 0x003C003C) | 0x42004200))

#define LDB(P, s) {                                        \
    P[0] = qwu[qi[0] + (size_t)(s) * STRD];                \
    P[1] = qwu[qi[1] + (size_t)(s) * STRD];                \
    P[2] = qwu[qi[2] + (size_t)(s) * STRD];                \
    P[3] = qwu[qi[3] + (size_t)(s) * STRD];                \
    P[4] = qwu[qi[4] + (size_t)(s) * STRD];                \
    P[5] = qwu[qi[5] + (size_t)(s) * STRD];                \
    P[6] = qwu[qi[6] + (size_t)(s) * STRD];                \
    P[7] = qwu[qi[7] + (size_t)(s) * STRD]; }

#define LDA(A, s) {                                                        \
    A[0] = *reinterpret_cast<const frag_ab*>(ab[0] + (size_t)(s) * 32);    \
    A[1] = *reinterpret_cast<const frag_ab*>(ab[1] + (size_t)(s) * 32);    \
    A[2] = *reinterpret_cast<const frag_ab*>(ab[2] + (size_t)(s) * 32);    \
    A[3] = *reinterpret_cast<const frag_ab*>(ab[3] + (size_t)(s) * 32); }

// One 32-k step: consume (P, A) for step s; optionally prefetch step s+4
// into the same (now-free) register sets.  Copies are SSA-renamed (free).
#define STEP(P, A, s, PF) {                                                  \
    u32 t0 = P[0], t1 = P[1], t2 = P[2], t3 = P[3];                          \
    u32 t4 = P[4], t5 = P[5], t6 = P[6], t7 = P[7];                          \
    frag_ab f0 = A[0], f1 = A[1], f2 = A[2], f3 = A[3];                      \
    if (PF) { LDB(P, (s) + 4); LDA(A, (s) + 4); }                            \
    union { frag_ab f; u32 u[4]; } b0, b1;                                   \
    b0.u[0] = BFCVT(t0); b0.u[1] = BFCVT(t1);                                \
    b0.u[2] = BFCVT(t2); b0.u[3] = BFCVT(t3);                                \
    b1.u[0] = BFCVT(t4); b1.u[1] = BFCVT(t5);                                \
    b1.u[2] = BFCVT(t6); b1.u[3] = BFCVT(t7);                                \
    acc[0][0] = __builtin_amdgcn_mfma_f32_16x16x32_bf16(f0, b0.f, acc[0][0], 0, 0, 0); \
    acc[0][1] = __builtin_amdgcn_mfma_f32_16x16x32_bf16(f0, b1.f, acc[0][1], 0, 0, 0); \
    acc[1][0] = __builtin_amdgcn_mfma_f32_16x16x32_bf16(f1, b0.f, acc[1][0], 0, 0, 0); \
    acc[1][1] = __builtin_amdgcn_mfma_f32_16x16x32_bf16(f1, b1.f, acc[1][1], 0, 0, 0); \
    acc[2][0] = __builtin_amdgcn_mfma_f32_16x16x32_bf16(f2, b0.f, acc[2][0], 0, 0, 0); \
    acc[2][1] = __builtin_amdgcn_mfma_f32_16x16x32_bf16(f2, b1.f, acc[2][1], 0, 0, 0); \
    acc[3][0] = __builtin_amdgcn_mfma_f32_16x16x32_bf16(f3, b0.f, acc[3][0], 0, 0, 0); \
    acc[3][1] = __builtin_amdgcn_mfma_f32_16x16x32_bf16(f3, b1.f, acc[3][1], 0, 0, 0); }

// Kernel 2: out = xbf @ dequant(qw).  Tile 128x64, 344 blocks (=8*43),
// 4 waves of 64m x 32n.  No LDS, no barriers: A-fragments and packed-B
// dwords stream global->register, software-pipelined 4 steps (128 k) deep.
__global__ __launch_bounds__(256) void gemm_kernel(const int* __restrict__ qw,
                                                   const float* __restrict__ scales,
                                                   const float* __restrict__ zeroes,
                                                   const ushort* __restrict__ xbf,
                                                   const float* __restrict__ rowsum,
                                                   float* __restrict__ out) {
    const u32* qwu = (const u32*)qw;
    const int tid  = threadIdx.x;
    const int lane = tid & 63;
    const int wid  = tid >> 6;
    const int l4   = lane & 15;
    const int c    = lane >> 4;

    // XCD-bijective swizzle (344 = 8*43): consecutive wg (the two M-halves
    // of one n-tile) land on the same XCD -> qweight L2 reuse.
    const int orig = blockIdx.x;
    const int wg   = (orig & 7) * 43 + (orig >> 3);
    const int nb   = wg >> 1;
    const int mb   = wg & 1;
    const int wm   = wid >> 1;
    const int wn   = wid & 1;
    const int m0   = mb * 128 + wm * 64;
    const int n0   = nb * 64 + wn * 32;

    // A: lane holds A[m = m0+mf*16+l4][k = s*32 + c*8 .. +7]
    const ushort* ab[4];
#pragma unroll
    for (int mf = 0; mf < 4; ++mf)
        ab[mf] = xbf + (size_t)(m0 + mf * 16 + l4) * K_DIM + c * 8;

    // B: packed dword (k-pair row c*4+p, col n0+nf*16+l4); i = nf*4+p
    int qi[8];
#pragma unroll
    for (int nf = 0; nf < 2; ++nf)
#pragma unroll
        for (int p = 0; p < 4; ++p)
            qi[nf * 4 + p] = (c * 4 + p) * N_DIM + n0 + nf * 16 + l4;

    frag_cd acc[4][2];
#pragma unroll
    for (int i = 0; i < 4; ++i) {
        acc[i][0] = (frag_cd){0.f, 0.f, 0.f, 0.f};
        acc[i][1] = (frag_cd){0.f, 0.f, 0.f, 0.f};
    }

    u32 q0[8], q1[8], q2[8], q3[8];
    frag_ab a0[4], a1[4], a2[4], a3[4];

    // prologue: fill the 4-deep pipeline
    LDB(q0, 0); LDB(q1, 1); LDB(q2, 2); LDB(q3, 3);
    LDA(a0, 0); LDA(a1, 1); LDA(a2, 2); LDA(a3, 3);

    for (int ss = 0; ss < NS - 4; ss += 4) {
        STEP(q0, a0, ss + 0, 1);
        STEP(q1, a1, ss + 1, 1);
        STEP(q2, a2, ss + 2, 1);
        STEP(q3, a3, ss + 3, 1);
    }
    STEP(q0, a0, NS - 4, 0);
    STEP(q1, a1, NS - 3, 0);
    STEP(q2, a2, NS - 2, 0);
    STEP(q3, a3, NS - 1, 0);

    // epilogue: out = sc*acc - (32*sc + zero)*rowsum
    float sc[2], zp[2];
#pragma unroll
    for (int nf = 0; nf < 2; ++nf) {
        int n = n0 + nf * 16 + l4;
        sc[nf] = scales[n];
        zp[nf] = zeroes[n] + 32.0f * sc[nf];
    }
    float rs[4][4];
#pragma unroll
    for (int mf = 0; mf < 4; ++mf)
#pragma unroll
        for (int j = 0; j < 4; ++j)
            rs[mf][j] = rowsum[m0 + mf * 16 + c * 4 + j];
#pragma unroll
    for (int mf = 0; mf < 4; ++mf)
#pragma unroll
        for (int nf = 0; nf < 2; ++nf)
#pragma unroll
            for (int j = 0; j < 4; ++j) {
                int m = m0 + mf * 16 + c * 4 + j;
                out[(size_t)m * N_DIM + n0 + nf * 16 + l4] =
                    sc[nf] * acc[mf][nf][j] - zp[nf] * rs[mf][j];
            }
}

extern "C" void kernel_launch(void* const* d_in, const int* in_sizes, int n_in,
                              void* d_out, int out_size, void* d_ws, size_t ws_size,
                              hipStream_t stream) {
    const float* x      = (const float*)d_in[0];
    const int*   qw     = (const int*)d_in[1];
    const float* scales = (const float*)d_in[2];
    const float* zeroes = (const float*)d_in[3];
    float* out = (float*)d_out;

    ushort* xbf    = (ushort*)d_ws;                                     // 2 MB
    float*  rowsum = (float*)((char*)d_ws + (size_t)M_DIM * K_DIM * 2); // 1 KB

    prep_kernel<<<M_DIM, 256, 0, stream>>>(x, xbf, rowsum);
    gemm_kernel<<<344, 256, 0, stream>>>(qw, scales, zeroes, xbf, rowsum, out);
}

// Round 4
// 74.007 us; speedup vs baseline: 2.1255x; 1.9109x over previous
//
#include <hip/hip_runtime.h>
#include <stdint.h>

#define K_DIM 4096
#define N_DIM 11008
#define M_DIM 256
#define NT 64            // 64 K-tiles of BK=64

typedef uint32_t u32;
using frag_ab = __attribute__((ext_vector_type(8))) short;   // 8 bf16
using frag_cd = __attribute__((ext_vector_type(4))) float;   // 4 f32

__device__ __forceinline__ u32 f2bf_rn(float f) {
    u32 u = __builtin_bit_cast(u32, f);
    return (u + 0x7FFFu + ((u >> 16) & 1u)) >> 16;   // round-to-nearest-even
}
__device__ __forceinline__ float bf2f(u32 b) {
    return __builtin_bit_cast(float, b << 16);
}
__device__ __forceinline__ void gll16(const void* g, void* l) {
    __builtin_amdgcn_global_load_lds(
        (const __attribute__((address_space(1))) u32*)g,
        (__attribute__((address_space(3))) u32*)l, 16, 0, 0);
}

// bf16(32+v) = 0x4200 | (v<<2).  For packed byte q = hi<<4|lo:
// q*0x4004 = q<<14 | q<<2 (no carries); mask -> {32+lo, 32+hi} bf16x2.
#define BFCVT(q) ((u32)((__mul24((int)(q), 0x4004) & 0x003C003C) | 0x42004200))

// Kernel 1: x f32 -> bf16 (RN) + per-row sums of the ROUNDED values (so the
// +32 trick's rank-1 correction cancels exactly).
__global__ __launch_bounds__(256) void prep_kernel(const float* __restrict__ x,
                                                   ushort* __restrict__ xbf,
                                                   float* __restrict__ rowsum) {
    const int row = blockIdx.x;
    const int tid = threadIdx.x;
    const float* xr = x + (size_t)row * K_DIM;
    ushort* br = xbf + (size_t)row * K_DIM;
    float s = 0.0f;
#pragma unroll
    for (int p = 0; p < 4; ++p) {
        int i = p * 1024 + tid * 4;
        float4 v = *reinterpret_cast<const float4*>(xr + i);
        u32 b0 = f2bf_rn(v.x), b1 = f2bf_rn(v.y), b2 = f2bf_rn(v.z), b3 = f2bf_rn(v.w);
        uint2 o;
        o.x = b0 | (b1 << 16);
        o.y = b2 | (b3 << 16);
        *reinterpret_cast<uint2*>(br + i) = o;
        s += bf2f(b0) + bf2f(b1) + bf2f(b2) + bf2f(b3);
    }
#pragma unroll
    for (int off = 32; off > 0; off >>= 1) s += __shfl_down(s, off, 64);
    __shared__ float wsum[4];
    if ((tid & 63) == 0) wsum[tid >> 6] = s;
    __syncthreads();
    if (tid == 0) rowsum[row] = wsum[0] + wsum[1] + wsum[2] + wsum[3];
}

// Kernel 2: out = xbf @ dequant(qw).  m97-style: BM=128, BN=64, BK=64,
// 4 waves (2m x 2n), wave tile 64x32.  A and packed-B staged into
// double-buffered LDS via global_load_lds(16B); consume-side int4->bf16
// unpack; both-sides XOR swizzle for conflict-free ds_reads.
__global__ __launch_bounds__(256, 3) void gemm_kernel(const int* __restrict__ qw,
                                                      const float* __restrict__ scales,
                                                      const float* __restrict__ zeroes,
                                                      const ushort* __restrict__ xbf,
                                                      const float* __restrict__ rowsum,
                                                      float* __restrict__ out) {
    // A tile: [m 0..127][chunk 0..7] of 16B (8 bf16), stored chunk ^= (m&7)
    // B tile: [row 0..31][col 0..63] packed dwords, stored col ^= ((row>>2&1)<<4)
    __shared__ uint4 Alds[2][1024];   // 2 x 16 KB
    __shared__ u32   Blds[2][2048];   // 2 x  8 KB

    const u32* qwu = (const u32*)qw;
    const int tid  = threadIdx.x;
    const int lane = tid & 63;
    const int wid  = tid >> 6;
    const int l4   = lane & 15;
    const int c    = lane >> 4;

    // XCD-bijective swizzle (344 = 8*43); mb-pair of one n-tile -> same XCD.
    const int orig = blockIdx.x;
    const int wg   = (orig & 7) * 43 + (orig >> 3);
    const int nb   = wg >> 1;
    const int mb   = wg & 1;
    const int n0   = nb * 64;
    const int m0   = mb * 128;
    const int wm   = wid >> 1;
    const int wn   = wid & 1;

    // ---- staging sources (pre-swizzled so linear LDS dest = swizzled layout)
    // A instr j: lane covers m = j*32 + wid*8 + (lane>>3), chunk (lane&7)^(lane>>3)
    const ushort* asrc[4];
#pragma unroll
    for (int j = 0; j < 4; ++j)
        asrc[j] = xbf + (size_t)(m0 + j * 32 + wid * 8 + (lane >> 3)) * K_DIM +
                  ((lane & 7) ^ (lane >> 3)) * 8;
    // B instr j: row = j*16 + wid*4 + (lane>>4); (row>>2)&1 == wid&1
    const u32* bsrc[2];
#pragma unroll
    for (int j = 0; j < 2; ++j)
        bsrc[j] = qwu + (size_t)(j * 16 + wid * 4 + (lane >> 4)) * N_DIM + n0 +
                  4 * ((lane & 15) ^ ((wid & 1) << 2));

    frag_cd acc[4][2];
#pragma unroll
    for (int i = 0; i < 4; ++i) {
        acc[i][0] = (frag_cd){0.f, 0.f, 0.f, 0.f};
        acc[i][1] = (frag_cd){0.f, 0.f, 0.f, 0.f};
    }

    auto stage = [&](int t, int buf) {
#pragma unroll
        for (int j = 0; j < 4; ++j)
            gll16(asrc[j] + t * 64, &Alds[buf][j * 256 + wid * 64]);
#pragma unroll
        for (int j = 0; j < 2; ++j)
            gll16(bsrc[j] + (size_t)t * 32 * N_DIM, &Blds[buf][(j * 256 + wid * 64) * 4]);
    };

    auto compute = [&](int buf) {
        frag_ab af[4][2];
#pragma unroll
        for (int mf = 0; mf < 4; ++mf)
#pragma unroll
            for (int ks = 0; ks < 2; ++ks) {
                int m_local = wm * 64 + mf * 16 + l4;
                int chunk   = (ks * 4 + c) ^ (l4 & 7);
                af[mf][ks]  = *reinterpret_cast<const frag_ab*>(
                    &Alds[buf][m_local * 8 + chunk]);
            }
#pragma unroll
        for (int ks = 0; ks < 2; ++ks)
#pragma unroll
            for (int nf = 0; nf < 2; ++nf) {
                int colsw = (wn * 32 + nf * 16 + l4) ^ ((c & 1) << 4);
                const u32* p = &Blds[buf][(ks * 16 + c * 4) * 64 + colsw];
                u32 q0 = p[0], q1 = p[64], q2 = p[128], q3 = p[192];
                union { frag_ab f; u32 u[4]; } bb;
                bb.u[0] = BFCVT(q0);
                bb.u[1] = BFCVT(q1);
                bb.u[2] = BFCVT(q2);
                bb.u[3] = BFCVT(q3);
#pragma unroll
                for (int mf = 0; mf < 4; ++mf)
                    acc[mf][nf] = __builtin_amdgcn_mfma_f32_16x16x32_bf16(
                        af[mf][ks], bb.f, acc[mf][nf], 0, 0, 0);
            }
    };

    // prologue
    stage(0, 0);
    __syncthreads();

    // 2-phase double-buffered pipeline, one barrier per tile
    for (int t = 0; t < NT; t += 2) {
        if (t + 1 < NT) stage(t + 1, 1);
        compute(0);
        __syncthreads();
        if (t + 1 < NT) {
            if (t + 2 < NT) stage(t + 2, 0);
            compute(1);
            __syncthreads();
        }
    }

    // epilogue: out = sc*acc - (32*sc + zero)*rowsum
    float sc[2], zp[2];
#pragma unroll
    for (int nf = 0; nf < 2; ++nf) {
        int n = n0 + wn * 32 + nf * 16 + l4;
        sc[nf] = scales[n];
        zp[nf] = zeroes[n] + 32.0f * sc[nf];
    }
    float rs[4][4];
#pragma unroll
    for (int mf = 0; mf < 4; ++mf)
#pragma unroll
        for (int j = 0; j < 4; ++j)
            rs[mf][j] = rowsum[m0 + wm * 64 + mf * 16 + c * 4 + j];
#pragma unroll
    for (int mf = 0; mf < 4; ++mf)
#pragma unroll
        for (int nf = 0; nf < 2; ++nf)
#pragma unroll
            for (int j = 0; j < 4; ++j) {
                int m = m0 + wm * 64 + mf * 16 + c * 4 + j;
                out[(size_t)m * N_DIM + n0 + wn * 32 + nf * 16 + l4] =
                    sc[nf] * acc[mf][nf][j] - zp[nf] * rs[mf][j];
            }
}

extern "C" void kernel_launch(void* const* d_in, const int* in_sizes, int n_in,
                              void* d_out, int out_size, void* d_ws, size_t ws_size,
                              hipStream_t stream) {
    const float* x      = (const float*)d_in[0];
    const int*   qw     = (const int*)d_in[1];
    const float* scales = (const float*)d_in[2];
    const float* zeroes = (const float*)d_in[3];
    float* out = (float*)d_out;

    ushort* xbf    = (ushort*)d_ws;                                     // 2 MB
    float*  rowsum = (float*)((char*)d_ws + (size_t)M_DIM * K_DIM * 2); // 1 KB

    prep_kernel<<<M_DIM, 256, 0, stream>>>(x, xbf, rowsum);
    gemm_kernel<<<344, 256, 0, stream>>>(qw, scales, zeroes, xbf, rowsum, out);
}

// Round 6
// 73.444 us; speedup vs baseline: 2.1418x; 1.0077x over previous
//
#include <hip/hip_runtime.h>
#include <stdint.h>

#define K_DIM 4096
#define N_DIM 11008
#define M_DIM 256

typedef uint32_t u32;
using frag_ab = __attribute__((ext_vector_type(8))) short;   // 8 bf16
using frag_cd = __attribute__((ext_vector_type(4))) float;   // 4 f32

__device__ __forceinline__ u32 f2bf_rn(float f) {
    u32 u = __builtin_bit_cast(u32, f);
    return (u + 0x7FFFu + ((u >> 16) & 1u)) >> 16;   // round-to-nearest-even
}
__device__ __forceinline__ float bf2f(u32 b) {
    return __builtin_bit_cast(float, b << 16);
}
__device__ __forceinline__ void gll16(const void* g, void* l) {
    __builtin_amdgcn_global_load_lds(
        (const __attribute__((address_space(1))) u32*)g,
        (__attribute__((address_space(3))) u32*)l, 16, 0, 0);
}

// bf16(32+v) = 0x4200 | (v<<2).  For packed byte q = hi<<4|lo:
// q*0x4004 = q<<14 | q<<2 (no carries); mask -> {32+lo, 32+hi} bf16x2.
#define BFCVT(q) ((u32)((__mul24((int)(q), 0x4004) & 0x003C003C) | 0x42004200))

// Kernel 1: x f32 -> bf16 (RN) + per-row sums of the ROUNDED values (so the
// +32 trick's rank-1 correction cancels exactly).
__global__ __launch_bounds__(256) void prep_kernel(const float* __restrict__ x,
                                                   ushort* __restrict__ xbf,
                                                   float* __restrict__ rowsum) {
    const int row = blockIdx.x;
    const int tid = threadIdx.x;
    const float* xr = x + (size_t)row * K_DIM;
    ushort* br = xbf + (size_t)row * K_DIM;
    float s = 0.0f;
#pragma unroll
    for (int p = 0; p < 4; ++p) {
        int i = p * 1024 + tid * 4;
        float4 v = *reinterpret_cast<const float4*>(xr + i);
        u32 b0 = f2bf_rn(v.x), b1 = f2bf_rn(v.y), b2 = f2bf_rn(v.z), b3 = f2bf_rn(v.w);
        uint2 o;
        o.x = b0 | (b1 << 16);
        o.y = b2 | (b3 << 16);
        *reinterpret_cast<uint2*>(br + i) = o;
        s += bf2f(b0) + bf2f(b1) + bf2f(b2) + bf2f(b3);
    }
#pragma unroll
    for (int off = 32; off > 0; off >>= 1) s += __shfl_down(s, off, 64);
    __shared__ float wsum[4];
    if ((tid & 63) == 0) wsum[tid >> 6] = s;
    __syncthreads();
    if (tid == 0) rowsum[row] = wsum[0] + wsum[1] + wsum[2] + wsum[3];
}

// Kernel 2: out = xbf @ dequant(qw).  BM=128, BN=64, BK=64, optional
// split-K=2.  4 waves (2m x 2n), wave tile 64x32.  A and packed-B staged
// into TRIPLE-buffered LDS via global_load_lds(16B), prefetched 2 tiles
// ahead with counted vmcnt + raw s_barrier (loads stay in flight across
// barriers).  Consume-side int4->bf16 unpack; both-sides XOR swizzle.
__global__ __launch_bounds__(256, 2) void gemm_kernel(const int* __restrict__ qw,
                                                      const float* __restrict__ scales,
                                                      const float* __restrict__ zeroes,
                                                      const ushort* __restrict__ xbf,
                                                      const float* __restrict__ rowsum,
                                                      float* __restrict__ out,
                                                      float* __restrict__ partial,
                                                      int split2) {
    // A tile: [m 0..127][chunk 0..7] of 16B (8 bf16), stored chunk ^= (m&7)
    // B tile: [row 0..31][col 0..63] packed dwords, stored col ^= ((row>>2&1)<<4)
    __shared__ uint4 Alds[3][1024];   // 3 x 16 KB
    __shared__ u32   Blds[3][2048];   // 3 x  8 KB

    const u32* qwu = (const u32*)qw;
    const int tid  = threadIdx.x;
    const int lane = tid & 63;
    const int wid  = tid >> 6;
    const int l4   = lane & 15;
    const int c    = lane >> 4;

    // XCD-bijective swizzle; all blocks of one n-tile land on the same XCD.
    const int orig = blockIdx.x;
    int nb, mb, sp, NTt;
    if (split2) {
        int wg = (orig & 7) * 86 + (orig >> 3);   // 688 = 8*86
        nb = wg >> 2; mb = (wg >> 1) & 1; sp = wg & 1; NTt = 32;
    } else {
        int wg = (orig & 7) * 43 + (orig >> 3);   // 344 = 8*43
        nb = wg >> 1; mb = wg & 1; sp = 0; NTt = 64;
    }
    const int n0 = nb * 64;
    const int m0 = mb * 128;
    const int kb = sp * 32;          // tile index base (tiles of 64 k)
    const int wm = wid >> 1;
    const int wn = wid & 1;

    // ---- staging sources (pre-swizzled so linear LDS dest = swizzled layout)
    const ushort* asrc[4];
#pragma unroll
    for (int j = 0; j < 4; ++j)
        asrc[j] = xbf + (size_t)(m0 + j * 32 + wid * 8 + (lane >> 3)) * K_DIM +
                  ((lane & 7) ^ (lane >> 3)) * 8;
    const u32* bsrc[2];
#pragma unroll
    for (int j = 0; j < 2; ++j)
        bsrc[j] = qwu + (size_t)(j * 16 + wid * 4 + (lane >> 4)) * N_DIM + n0 +
                  4 * ((lane & 15) ^ ((wid & 1) << 2));

    frag_cd acc[4][2];
#pragma unroll
    for (int i = 0; i < 4; ++i) {
        acc[i][0] = (frag_cd){0.f, 0.f, 0.f, 0.f};
        acc[i][1] = (frag_cd){0.f, 0.f, 0.f, 0.f};
    }

    auto stage = [&](int t_abs, int buf) {     // 6 x global_load_lds(16B)
#pragma unroll
        for (int j = 0; j < 4; ++j)
            gll16(asrc[j] + (size_t)t_abs * 64, &Alds[buf][j * 256 + wid * 64]);
#pragma unroll
        for (int j = 0; j < 2; ++j)
            gll16(bsrc[j] + (size_t)t_abs * 32 * N_DIM,
                  &Blds[buf][(j * 256 + wid * 64) * 4]);
    };

    auto compute = [&](int buf) {
        frag_ab af[4][2];
#pragma unroll
        for (int mf = 0; mf < 4; ++mf)
#pragma unroll
            for (int ks = 0; ks < 2; ++ks) {
                int m_local = wm * 64 + mf * 16 + l4;
                int chunk   = (ks * 4 + c) ^ (l4 & 7);
                af[mf][ks]  = *reinterpret_cast<const frag_ab*>(
                    &Alds[buf][m_local * 8 + chunk]);
            }
#pragma unroll
        for (int ks = 0; ks < 2; ++ks)
#pragma unroll
            for (int nf = 0; nf < 2; ++nf) {
                int colsw = (wn * 32 + nf * 16 + l4) ^ ((c & 1) << 4);
                const u32* p = &Blds[buf][(ks * 16 + c * 4) * 64 + colsw];
                u32 q0 = p[0], q1 = p[64], q2 = p[128], q3 = p[192];
                union { frag_ab f; u32 u[4]; } bb;
                bb.u[0] = BFCVT(q0);
                bb.u[1] = BFCVT(q1);
                bb.u[2] = BFCVT(q2);
                bb.u[3] = BFCVT(q3);
#pragma unroll
                for (int mf = 0; mf < 4; ++mf)
                    acc[mf][nf] = __builtin_amdgcn_mfma_f32_16x16x32_bf16(
                        af[mf][ks], bb.f, acc[mf][nf], 0, 0, 0);
            }
    };

    // prologue: fill 2-deep prefetch
    stage(kb + 0, 0);
    if (NTt > 1) stage(kb + 1, 1);

    int cur = 0;
    for (int t = 0; t < NTt; ++t) {
        int pbuf = cur + 2; if (pbuf >= 3) pbuf -= 3;
        if (t + 2 < NTt) {
            stage(kb + t + 2, pbuf);
            asm volatile("s_waitcnt vmcnt(12)" ::: "memory");  // keep 2 tiles in flight
        } else if (t + 1 < NTt) {
            asm volatile("s_waitcnt vmcnt(6)" ::: "memory");
        } else {
            asm volatile("s_waitcnt vmcnt(0)" ::: "memory");
        }
        __builtin_amdgcn_s_barrier();        // tile t's LDS writes visible
        compute(cur);
        asm volatile("" ::: "memory");
        __builtin_amdgcn_s_barrier();        // all waves done reading buf before re-stage
        ++cur; if (cur >= 3) cur -= 3;
    }

    // epilogue
    float sc[2], zp[2];
#pragma unroll
    for (int nf = 0; nf < 2; ++nf) {
        int n = n0 + wn * 32 + nf * 16 + l4;
        sc[nf] = scales[n];
        zp[nf] = zeroes[n] + 32.0f * sc[nf];
    }
    if (sp == 0) {
        float rs[4][4];
#pragma unroll
        for (int mf = 0; mf < 4; ++mf)
#pragma unroll
            for (int j = 0; j < 4; ++j)
                rs[mf][j] = rowsum[m0 + wm * 64 + mf * 16 + c * 4 + j];
#pragma unroll
        for (int mf = 0; mf < 4; ++mf)
#pragma unroll
            for (int nf = 0; nf < 2; ++nf)
#pragma unroll
                for (int j = 0; j < 4; ++j) {
                    int m = m0 + wm * 64 + mf * 16 + c * 4 + j;
                    out[(size_t)m * N_DIM + n0 + wn * 32 + nf * 16 + l4] =
                        sc[nf] * acc[mf][nf][j] - zp[nf] * rs[mf][j];
                }
    } else {
#pragma unroll
        for (int mf = 0; mf < 4; ++mf)
#pragma unroll
            for (int nf = 0; nf < 2; ++nf)
#pragma unroll
                for (int j = 0; j < 4; ++j) {
                    int m = m0 + wm * 64 + mf * 16 + c * 4 + j;
                    partial[(size_t)m * N_DIM + n0 + wn * 32 + nf * 16 + l4] =
                        sc[nf] * acc[mf][nf][j];
                }
    }
}

// Kernel 3: out += partial.  Exact cover of 256*11008 floats:
// 2752 blocks * 256 threads * 4 floats = 2,818,048.
__global__ __launch_bounds__(256) void reduce_kernel(float* __restrict__ out,
                                                     const float* __restrict__ partial) {
    size_t i = ((size_t)blockIdx.x * 256 + threadIdx.x) * 4;
    float4 o = *reinterpret_cast<float4*>(out + i);
    float4 p = *reinterpret_cast<const float4*>(partial + i);
    o.x += p.x; o.y += p.y; o.z += p.z; o.w += p.w;
    *reinterpret_cast<float4*>(out + i) = o;
}

extern "C" void kernel_launch(void* const* d_in, const int* in_sizes, int n_in,
                              void* d_out, int out_size, void* d_ws, size_t ws_size,
                              hipStream_t stream) {
    const float* x      = (const float*)d_in[0];
    const int*   qw     = (const int*)d_in[1];
    const float* scales = (const float*)d_in[2];
    const float* zeroes = (const float*)d_in[3];
    float* out = (float*)d_out;

    const size_t XBF_BYTES = (size_t)M_DIM * K_DIM * 2;   // 2 MB
    const size_t RS_OFF    = XBF_BYTES;                    // 1 KB
    const size_t P_OFF     = XBF_BYTES + 4096;
    const size_t P_BYTES   = (size_t)M_DIM * N_DIM * 4;    // 11.3 MB

    ushort* xbf    = (ushort*)d_ws;
    float*  rowsum = (float*)((char*)d_ws + RS_OFF);
    float*  part   = (float*)((char*)d_ws + P_OFF);

    const bool split2 = ws_size >= P_OFF + P_BYTES;

    prep_kernel<<<M_DIM, 256, 0, stream>>>(x, xbf, rowsum);
    if (split2) {
        gemm_kernel<<<688, 256, 0, stream>>>(qw, scales, zeroes, xbf, rowsum,
                                             out, part, 1);
        reduce_kernel<<<(M_DIM * N_DIM) / (256 * 4), 256, 0, stream>>>(out, part);
    } else {
        gemm_kernel<<<344, 256, 0, stream>>>(qw, scales, zeroes, xbf, rowsum,
                                             out, nullptr, 0);
    }
}

// Round 7
// 56.206 us; speedup vs baseline: 2.7987x; 1.3067x over previous
//
#include <hip/hip_runtime.h>
#include <stdint.h>

#define K_DIM 4096
#define N_DIM 11008
#define M_DIM 256

typedef uint32_t u32;
using frag_ab = __attribute__((ext_vector_type(8))) short;   // 8 bf16
using frag_cd = __attribute__((ext_vector_type(4))) float;   // 4 f32
using u32x2   = __attribute__((ext_vector_type(2))) uint32_t;

typedef __attribute__((address_space(3))) const char lds_cc;

// Inline-asm LDS reads: opaque to the compiler's waitcnt pass, so our counted
// vmcnt (not an auto-inserted vmcnt(0)) governs the global_load_lds queue.
#define DSR128(dst, addr, off)                                       \
    asm volatile("ds_read_b128 %0, %1 offset:" #off                  \
                 : "=&v"(dst) : "v"(addr))
#define DSR2(dst, addr, o0, o1)                                      \
    asm volatile("ds_read2_b32 %0, %1 offset0:" #o0 " offset1:" #o1  \
                 : "=&v"(dst) : "v"(addr))

__device__ __forceinline__ u32 f2bf_rn(float f) {
    u32 u = __builtin_bit_cast(u32, f);
    return (u + 0x7FFFu + ((u >> 16) & 1u)) >> 16;   // round-to-nearest-even
}
__device__ __forceinline__ float bf2f(u32 b) {
    return __builtin_bit_cast(float, b << 16);
}
__device__ __forceinline__ void gll16(const void* g, void* l) {
    __builtin_amdgcn_global_load_lds(
        (const __attribute__((address_space(1))) u32*)g,
        (__attribute__((address_space(3))) u32*)l, 16, 0, 0);
}

// bf16(32+v) = 0x4200 | (v<<2).  For packed byte q = hi<<4|lo:
// q*0x4004 = q<<14 | q<<2 (no carries); mask -> {32+lo, 32+hi} bf16x2.
#define BFCVT(q) ((u32)((__mul24((int)(q), 0x4004) & 0x003C003C) | 0x42004200))

// Kernel 1: x f32 -> bf16 (RN) + per-row sums of the ROUNDED values.
__global__ __launch_bounds__(256) void prep_kernel(const float* __restrict__ x,
                                                   ushort* __restrict__ xbf,
                                                   float* __restrict__ rowsum) {
    const int row = blockIdx.x;
    const int tid = threadIdx.x;
    const float* xr = x + (size_t)row * K_DIM;
    ushort* br = xbf + (size_t)row * K_DIM;
    float s = 0.0f;
#pragma unroll
    for (int p = 0; p < 4; ++p) {
        int i = p * 1024 + tid * 4;
        float4 v = *reinterpret_cast<const float4*>(xr + i);
        u32 b0 = f2bf_rn(v.x), b1 = f2bf_rn(v.y), b2 = f2bf_rn(v.z), b3 = f2bf_rn(v.w);
        uint2 o;
        o.x = b0 | (b1 << 16);
        o.y = b2 | (b3 << 16);
        *reinterpret_cast<uint2*>(br + i) = o;
        s += bf2f(b0) + bf2f(b1) + bf2f(b2) + bf2f(b3);
    }
#pragma unroll
    for (int off = 32; off > 0; off >>= 1) s += __shfl_down(s, off, 64);
    __shared__ float wsum[4];
    if ((tid & 63) == 0) wsum[tid >> 6] = s;
    __syncthreads();
    if (tid == 0) rowsum[row] = wsum[0] + wsum[1] + wsum[2] + wsum[3];
}

// Kernel 2: out = xbf @ dequant(qw).  BM=128, BN=64, BK=64, split-K=2.
// Triple-buffered LDS via global_load_lds(16B), 2-tile prefetch, counted
// vmcnt + raw s_barrier; all LDS reads are inline asm so the prefetch queue
// is never drained by compiler-inserted vmcnt(0).
__global__ __launch_bounds__(256, 2) void gemm_kernel(const int* __restrict__ qw,
                                                      const float* __restrict__ scales,
                                                      const float* __restrict__ zeroes,
                                                      const ushort* __restrict__ xbf,
                                                      const float* __restrict__ rowsum,
                                                      float* __restrict__ out,
                                                      float* __restrict__ partial,
                                                      int split2) {
    // A tile: [m 0..127][chunk 0..7] of 16B (8 bf16), stored chunk ^= (m&7)
    // B tile: [row 0..31][col 0..63] packed dwords, stored col ^= ((row>>2&1)<<4)
    __shared__ uint4 Alds[3][1024];   // 3 x 16 KB
    __shared__ u32   Blds[3][2048];   // 3 x  8 KB

    const u32* qwu = (const u32*)qw;
    const int tid  = threadIdx.x;
    const int lane = tid & 63;
    const int wid  = tid >> 6;
    const int l4   = lane & 15;
    const int c    = lane >> 4;

    // XCD-bijective swizzle; all blocks of one n-tile land on the same XCD.
    const int orig = blockIdx.x;
    int nb, mb, sp, NTt;
    if (split2) {
        int wg = (orig & 7) * 86 + (orig >> 3);   // 688 = 8*86
        nb = wg >> 2; mb = (wg >> 1) & 1; sp = wg & 1; NTt = 32;
    } else {
        int wg = (orig & 7) * 43 + (orig >> 3);   // 344 = 8*43
        nb = wg >> 1; mb = wg & 1; sp = 0; NTt = 64;
    }
    const int n0 = nb * 64;
    const int m0 = mb * 128;
    const int kb = sp * 32;          // tile index base (tiles of 64 k)
    const int wm = wid >> 1;
    const int wn = wid & 1;

    // ---- staging sources (pre-swizzled so linear LDS dest = swizzled layout)
    const ushort* asrc[4];
#pragma unroll
    for (int j = 0; j < 4; ++j)
        asrc[j] = xbf + (size_t)(m0 + j * 32 + wid * 8 + (lane >> 3)) * K_DIM +
                  ((lane & 7) ^ (lane >> 3)) * 8;
    const u32* bsrc[2];
#pragma unroll
    for (int j = 0; j < 2; ++j)
        bsrc[j] = qwu + (size_t)(j * 16 + wid * 4 + (lane >> 4)) * N_DIM + n0 +
                  4 * ((lane & 15) ^ ((wid & 1) << 2));

    // ---- LDS read byte-offsets (within one buffer)
    const u32 aoff0 = (u32)((wm * 64 + l4) * 128 + (((0 * 4 + c) ^ (l4 & 7)) << 4));
    const u32 aoff1 = (u32)((wm * 64 + l4) * 128 + (((1 * 4 + c) ^ (l4 & 7)) << 4));
    u32 boffs[2][2];
#pragma unroll
    for (int nf = 0; nf < 2; ++nf)
#pragma unroll
        for (int ks = 0; ks < 2; ++ks)
            boffs[nf][ks] = (u32)(((ks * 16 + c * 4) * 64 +
                                   ((wn * 32 + nf * 16 + l4) ^ ((c & 1) << 4))) * 4);

    frag_cd acc[4][2];
#pragma unroll
    for (int i = 0; i < 4; ++i) {
        acc[i][0] = (frag_cd){0.f, 0.f, 0.f, 0.f};
        acc[i][1] = (frag_cd){0.f, 0.f, 0.f, 0.f};
    }

    auto stage = [&](int t_abs, int buf) {     // 6 x global_load_lds(16B)
#pragma unroll
        for (int j = 0; j < 4; ++j)
            gll16(asrc[j] + (size_t)t_abs * 64, &Alds[buf][j * 256 + wid * 64]);
#pragma unroll
        for (int j = 0; j < 2; ++j)
            gll16(bsrc[j] + (size_t)t_abs * 32 * N_DIM,
                  &Blds[buf][(j * 256 + wid * 64) * 4]);
    };

    auto compute = [&](int buf) {
        lds_cc* Ab = (lds_cc*)&Alds[buf][0];
        lds_cc* Bb = (lds_cc*)&Blds[buf][0];
        frag_ab afr[4][2];
        DSR128(afr[0][0], Ab + aoff0, 0);
        DSR128(afr[1][0], Ab + aoff0, 2048);
        DSR128(afr[2][0], Ab + aoff0, 4096);
        DSR128(afr[3][0], Ab + aoff0, 6144);
        DSR128(afr[0][1], Ab + aoff1, 0);
        DSR128(afr[1][1], Ab + aoff1, 2048);
        DSR128(afr[2][1], Ab + aoff1, 4096);
        DSR128(afr[3][1], Ab + aoff1, 6144);
        u32x2 br[2][2][2];               // [nf][ks][pair], pair j={0,1},{2,3}
        DSR2(br[0][0][0], Bb + boffs[0][0], 0, 64);
        DSR2(br[0][0][1], Bb + boffs[0][0], 128, 192);
        DSR2(br[1][0][0], Bb + boffs[1][0], 0, 64);
        DSR2(br[1][0][1], Bb + boffs[1][0], 128, 192);
        DSR2(br[0][1][0], Bb + boffs[0][1], 0, 64);
        DSR2(br[0][1][1], Bb + boffs[0][1], 128, 192);
        DSR2(br[1][1][0], Bb + boffs[1][1], 0, 64);
        DSR2(br[1][1][1], Bb + boffs[1][1], 128, 192);
        asm volatile("s_waitcnt lgkmcnt(0)" ::: "memory");
        __builtin_amdgcn_sched_barrier(0);   // rule #18: pin MFMA after the wait
#pragma unroll
        for (int ks = 0; ks < 2; ++ks)
#pragma unroll
            for (int nf = 0; nf < 2; ++nf) {
                union { frag_ab f; u32 u[4]; } bb;
                bb.u[0] = BFCVT(br[nf][ks][0][0]);
                bb.u[1] = BFCVT(br[nf][ks][0][1]);
                bb.u[2] = BFCVT(br[nf][ks][1][0]);
                bb.u[3] = BFCVT(br[nf][ks][1][1]);
#pragma unroll
                for (int mf = 0; mf < 4; ++mf)
                    acc[mf][nf] = __builtin_amdgcn_mfma_f32_16x16x32_bf16(
                        afr[mf][ks], bb.f, acc[mf][nf], 0, 0, 0);
            }
    };

    // prologue: fill 2-deep prefetch
    stage(kb + 0, 0);
    if (NTt > 1) stage(kb + 1, 1);

    int cur = 0;
    for (int t = 0; t < NTt; ++t) {
        int pbuf = cur + 2; if (pbuf >= 3) pbuf -= 3;
        if (t + 2 < NTt) {
            stage(kb + t + 2, pbuf);
            asm volatile("s_waitcnt vmcnt(12)" ::: "memory");  // keep 2 tiles in flight
        } else if (t + 1 < NTt) {
            asm volatile("s_waitcnt vmcnt(6)" ::: "memory");
        } else {
            asm volatile("s_waitcnt vmcnt(0)" ::: "memory");
        }
        __builtin_amdgcn_s_barrier();        // tile t's LDS writes visible
        __builtin_amdgcn_sched_barrier(0);
        compute(cur);
        asm volatile("" ::: "memory");
        __builtin_amdgcn_s_barrier();        // all waves done reading buf before re-stage
        ++cur; if (cur >= 3) cur -= 3;
    }

    // epilogue
    float sc[2], zp[2];
#pragma unroll
    for (int nf = 0; nf < 2; ++nf) {
        int n = n0 + wn * 32 + nf * 16 + l4;
        sc[nf] = scales[n];
        zp[nf] = zeroes[n] + 32.0f * sc[nf];
    }
    if (sp == 0) {
        float rs[4][4];
#pragma unroll
        for (int mf = 0; mf < 4; ++mf)
#pragma unroll
            for (int j = 0; j < 4; ++j)
                rs[mf][j] = rowsum[m0 + wm * 64 + mf * 16 + c * 4 + j];
#pragma unroll
        for (int mf = 0; mf < 4; ++mf)
#pragma unroll
            for (int nf = 0; nf < 2; ++nf)
#pragma unroll
                for (int j = 0; j < 4; ++j) {
                    int m = m0 + wm * 64 + mf * 16 + c * 4 + j;
                    out[(size_t)m * N_DIM + n0 + wn * 32 + nf * 16 + l4] =
                        sc[nf] * acc[mf][nf][j] - zp[nf] * rs[mf][j];
                }
    } else {
#pragma unroll
        for (int mf = 0; mf < 4; ++mf)
#pragma unroll
            for (int nf = 0; nf < 2; ++nf)
#pragma unroll
                for (int j = 0; j < 4; ++j) {
                    int m = m0 + wm * 64 + mf * 16 + c * 4 + j;
                    partial[(size_t)m * N_DIM + n0 + wn * 32 + nf * 16 + l4] =
                        sc[nf] * acc[mf][nf][j];
                }
    }
}

// Kernel 3: out += partial.  Exact cover of 256*11008 floats:
// 2752 blocks * 256 threads * 4 floats = 2,818,048.
__global__ __launch_bounds__(256) void reduce_kernel(float* __restrict__ out,
                                                     const float* __restrict__ partial) {
    size_t i = ((size_t)blockIdx.x * 256 + threadIdx.x) * 4;
    float4 o = *reinterpret_cast<float4*>(out + i);
    float4 p = *reinterpret_cast<const float4*>(partial + i);
    o.x += p.x; o.y += p.y; o.z += p.z; o.w += p.w;
    *reinterpret_cast<float4*>(out + i) = o;
}

extern "C" void kernel_launch(void* const* d_in, const int* in_sizes, int n_in,
                              void* d_out, int out_size, void* d_ws, size_t ws_size,
                              hipStream_t stream) {
    const float* x      = (const float*)d_in[0];
    const int*   qw     = (const int*)d_in[1];
    const float* scales = (const float*)d_in[2];
    const float* zeroes = (const float*)d_in[3];
    float* out = (float*)d_out;

    const size_t XBF_BYTES = (size_t)M_DIM * K_DIM * 2;   // 2 MB
    const size_t RS_OFF    = XBF_BYTES;                    // 1 KB
    const size_t P_OFF     = XBF_BYTES + 4096;
    const size_t P_BYTES   = (size_t)M_DIM * N_DIM * 4;    // 11.3 MB

    ushort* xbf    = (ushort*)d_ws;
    float*  rowsum = (float*)((char*)d_ws + RS_OFF);
    float*  part   = (float*)((char*)d_ws + P_OFF);

    const bool split2 = ws_size >= P_OFF + P_BYTES;

    prep_kernel<<<M_DIM, 256, 0, stream>>>(x, xbf, rowsum);
    if (split2) {
        gemm_kernel<<<688, 256, 0, stream>>>(qw, scales, zeroes, xbf, rowsum,
                                             out, part, 1);
        reduce_kernel<<<(M_DIM * N_DIM) / (256 * 4), 256, 0, stream>>>(out, part);
    } else {
        gemm_kernel<<<344, 256, 0, stream>>>(qw, scales, zeroes, xbf, rowsum,
                                             out, nullptr, 0);
    }
}